// Round 18
// baseline (221.377 us; speedup 1.0000x reference)
//
#include <hip/hip_runtime.h>
#include <hip/hip_bf16.h>

#define S 9216      // 96*96 spatial positions
#define C 256       // channels
#define NCT 6       // 256-col tiles per block (block = 64 rows x 1536 cols)
#define NG  (NCT*8) // kt-steps per block (48)
#define SCH 576     // s-chunk for rowsum/colmax kernels (grid 2304 = 9/CU)

typedef __bf16 bf16x8 __attribute__((ext_vector_type(8)));
typedef float f32x4 __attribute__((ext_vector_type(4)));
typedef unsigned short us8 __attribute__((ext_vector_type(8)));
typedef unsigned short us4 __attribute__((ext_vector_type(4)));

#define GLOAD_LDS16(g, l) __builtin_amdgcn_global_load_lds( \
    (const __attribute__((address_space(1))) void*)(g),     \
    (__attribute__((address_space(3))) void*)(l), 16, 0, 0)

#define A2C 2.8853900817779268f   // 2*log2(e) = 2/ln2

__device__ __forceinline__ float bf2f(unsigned short u) {
    return __uint_as_float(((unsigned)u) << 16);
}
__device__ __forceinline__ unsigned short f2bfbits(float x) {
    __hip_bfloat16 h = __float2bfloat16(x);
    return *reinterpret_cast<unsigned short*>(&h);
}

// ---------------- mean of gt over spatial, per channel ----------------
__global__ __launch_bounds__(256) void k_mean(const float* __restrict__ gt,
                                              float* __restrict__ meanT) {
    const int c = blockIdx.x;
    const float* p = gt + (size_t)c * S;
    float s = 0.f;
    for (int i = threadIdx.x; i < S; i += 256) s += p[i];
    for (int m = 1; m < 64; m <<= 1) s += __shfl_xor(s, m, 64);
    __shared__ float red[4];
    if ((threadIdx.x & 63) == 0) red[threadIdx.x >> 6] = s;
    __syncthreads();
    if (threadIdx.x == 0)
        meanT[c] = (red[0] + red[1] + red[2] + red[3]) * (1.0f / S);
}

// ------- center to bf16 A,B + partial ssq (+ fused reduction-buffer init) ---
// 576 blocks (16 parts x 36 s-blocks). Writes CENTERED bf16 (un-normalized);
// k_norm rescales in place — avoids re-reading the 72MB f32 inputs twice.
__global__ __launch_bounds__(256) void k_ssq(const float* __restrict__ img,
                                             const float* __restrict__ gt,
                                             const float* __restrict__ meanT,
                                             float* __restrict__ ssqP,     // [32][S]
                                             __hip_bfloat16* __restrict__ A,
                                             __hip_bfloat16* __restrict__ B,
                                             float* __restrict__ rowmin,
                                             float* __restrict__ rowsum,
                                             float* __restrict__ colmaxLog) {
    __shared__ float sm[16];
    const int part = blockIdx.x & 15;
    const int sb   = blockIdx.x >> 4;
    const int t    = threadIdx.x;
    if (t < 16) sm[t] = meanT[part * 16 + t];
    const int s = sb * 256 + t;
    if (part == 0) {
        rowmin[s]    = __uint_as_float(0x7f800000u);  // +inf
        rowsum[s]    = 0.f;
        colmaxLog[s] = 0.f;    // biased log2 max; 0 == 2^-64 ~ 0
    }
    __syncthreads();
    const int c0 = part * 16;
    float si = 0.f, st = 0.f;
    #pragma unroll
    for (int cc = 0; cc < 2; ++cc) {
        us8 va, vb;
        #pragma unroll
        for (int e = 0; e < 8; ++e) {
            const int c = c0 + cc * 8 + e;
            const float m  = sm[cc * 8 + e];
            const float di = img[(size_t)c * S + s] - m;
            const float dt = gt [(size_t)c * S + s] - m;
            si += di * di;
            st += dt * dt;
            va[e] = f2bfbits(di);
            vb[e] = f2bfbits(dt);
        }
        *reinterpret_cast<us8*>(A + (size_t)s * C + c0 + cc * 8) = va;
        *reinterpret_cast<us8*>(B + (size_t)s * C + c0 + cc * 8) = vb;
    }
    ssqP[(size_t)part * S + s]        = si;
    ssqP[(size_t)(part + 16) * S + s] = st;
}

// ---------------- normalize A,B in place (bf16 RMW, 40MB vs 83MB) ----------
__global__ __launch_bounds__(256) void k_norm(const float* __restrict__ ssqP,
                                              __hip_bfloat16* __restrict__ A,
                                              __hip_bfloat16* __restrict__ B) {
    const int part = blockIdx.x & 15;
    const int sb   = blockIdx.x >> 4;
    const int s    = sb * 256 + threadIdx.x;
    float si = 0.f, st = 0.f;
    #pragma unroll
    for (int p = 0; p < 16; ++p) {
        si += ssqP[(size_t)p * S + s];
        st += ssqP[(size_t)(p + 16) * S + s];
    }
    const float ri = 1.0f / fmaxf(sqrtf(si), 1e-12f);
    const float rt = 1.0f / fmaxf(sqrtf(st), 1e-12f);
    const int c0 = part * 16;
    #pragma unroll
    for (int cc = 0; cc < 2; ++cc) {
        us8 va = *reinterpret_cast<const us8*>(A + (size_t)s * C + c0 + cc * 8);
        us8 vb = *reinterpret_cast<const us8*>(B + (size_t)s * C + c0 + cc * 8);
        #pragma unroll
        for (int e = 0; e < 8; ++e) {
            va[e] = f2bfbits(bf2f(va[e]) * ri);
            vb[e] = f2bfbits(bf2f(vb[e]) * rt);
        }
        *reinterpret_cast<us8*>(A + (size_t)s * C + c0 + cc * 8) = va;
        *reinterpret_cast<us8*>(B + (size_t)s * C + c0 + cc * 8) = vb;
    }
}

// ---------------- GEMM pass: store raw^T + rowmin (r17, frozen) -------------
// 9 structural variants (r7-r17) all land 105-137us; this is the best (105).
__global__ __launch_bounds__(256, 2) void k_gemm_store(const __hip_bfloat16* __restrict__ A,
                                                       const __hip_bfloat16* __restrict__ B,
                                                       float* __restrict__ rowmin,
                                                       __hip_bfloat16* __restrict__ Q) {
    __shared__ alignas(16) __hip_bfloat16 As[64 * 256];        // 32 KB
    __shared__ alignas(16) __hip_bfloat16 Bs[4 * 2 * 2048];    // 32 KB
    const int tid  = threadIdx.x;
    const int lane = tid & 63;
    const int wid  = tid >> 6;
    const int orig = blockIdx.x;
    const int xcd  = orig & 7;
    const int q    = orig >> 3;                  // 0..107
    const int colGroup = q / 18;                 // 0..5
    const int strip    = xcd * 18 + (q % 18);    // 0..143
    const int rowBase = strip * 64;
    const int cb0     = colGroup * 1536;

    const int frow = lane & 15;
    const int kgrp = lane >> 4;

    {
        const int arow_lo = lane >> 5;
        const int achunk  = lane & 31;
        #pragma unroll
        for (int j = 0; j < 8; ++j) {
            const int row = wid * 16 + j * 2 + arow_lo;
            const int cc  = achunk ^ (row & 7);
            GLOAD_LDS16(A + (size_t)(rowBase + row) * C + cc * 8,
                        &As[(wid * 16 + j * 2) * 256 + lane * 8]);
        }
    }
    const int bcol4  = lane >> 2;
    const int bchunk = (lane & 3) ^ ((lane >> 3) & 3);
    __hip_bfloat16* const BsW = &Bs[wid * 4096];
    const __hip_bfloat16* const Bsrc = B + (size_t)(cb0 + wid * 64) * C;

#define STAGE_B(tt, kk, bb) do {                                              \
    _Pragma("unroll")                                                         \
    for (int i_ = 0; i_ < 4; ++i_) {                                          \
        GLOAD_LDS16(Bsrc + (size_t)((tt) * 256 + i_ * 16 + bcol4) * C         \
                         + (kk) * 32 + bchunk * 8,                            \
                    &BsW[(bb) * 2048 + i_ * 512]);                            \
    } } while (0)

    STAGE_B(0, 0, 0);
    STAGE_B(0, 1, 1);

    asm volatile("s_waitcnt vmcnt(4)" ::: "memory");
    __builtin_amdgcn_s_barrier();

    const int bswz = (kgrp ^ ((frow >> 1) & 3)) * 8;

    float vmin[4][4];
    #pragma unroll
    for (int m = 0; m < 4; ++m)
        #pragma unroll
        for (int qq = 0; qq < 4; ++qq) vmin[m][qq] = 1e30f;

    for (int t = 0; t < NCT; ++t) {
        f32x4 acc[4][4] = {};
        #pragma unroll
        for (int kt = 0; kt < 8; ++kt) {
            if (t > 0 && kt < 2)               asm volatile("s_waitcnt vmcnt(20)" ::: "memory");
            else if (t == NCT - 1 && kt == 7)  asm volatile("s_waitcnt vmcnt(0)"  ::: "memory");
            else                               asm volatile("s_waitcnt vmcnt(4)"  ::: "memory");

            const int bufc = kt & 1;

            bf16x8 af[4], bfr[4];
            #pragma unroll
            for (int m = 0; m < 4; ++m) {
                const int row = m * 16 + frow;
                const int p   = (kt * 4 + kgrp) ^ (frow & 7);
                af[m] = *reinterpret_cast<const bf16x8*>(&As[row * 256 + p * 8]);
            }
            #pragma unroll
            for (int n = 0; n < 4; ++n)
                bfr[n] = *reinterpret_cast<const bf16x8*>(
                    &BsW[bufc * 2048 + (n * 16 + frow) * 32 + bswz]);

            asm volatile("s_waitcnt lgkmcnt(0)" ::: "memory");
            __builtin_amdgcn_sched_barrier(0);

            if (kt <= 5) {
                STAGE_B(t, kt + 2, bufc);
            } else if (t + 1 < NCT) {
                STAGE_B(t + 1, kt - 6, bufc);
            }

            #pragma unroll
            for (int m = 0; m < 4; ++m)
                #pragma unroll
                for (int n = 0; n < 4; ++n)
                    acc[m][n] = __builtin_amdgcn_mfma_f32_16x16x32_bf16(af[m], bfr[n], acc[m][n], 0, 0, 0);
        }

        const int colBase = cb0 + t * 256;
        #pragma unroll
        for (int n = 0; n < 4; ++n) {
            const int cg = colBase + wid * 64 + n * 16 + frow;
            #pragma unroll
            for (int m = 0; m < 4; ++m) {
                us4 pk;
                #pragma unroll
                for (int qq = 0; qq < 4; ++qq) {
                    const float raw = fmaxf(0.5f * (1.0f - acc[m][n][qq]), 0.0f);
                    vmin[m][qq] = fminf(vmin[m][qq], raw);
                    pk[qq] = f2bfbits(raw);
                }
                *reinterpret_cast<us4*>(Q + (size_t)cg * S + rowBase + m * 16 + kgrp * 4) = pk;
            }
        }
    }
#undef STAGE_B

    #pragma unroll
    for (int m = 0; m < 4; ++m)
        #pragma unroll
        for (int qq = 0; qq < 4; ++qq) {
            float v = vmin[m][qq];
            v = fminf(v, __shfl_xor(v, 1, 64));
            v = fminf(v, __shfl_xor(v, 2, 64));
            v = fminf(v, __shfl_xor(v, 4, 64));
            v = fminf(v, __shfl_xor(v, 8, 64));
            if (frow == 0)
                atomicMin((unsigned int*)&rowmin[rowBase + m * 16 + kgrp * 4 + qq],
                          __float_as_uint(v));
        }
}

// ---------------- rowsum over s-chunks (exp2 form) ------------
// 2304 blocks (144 r-strips x 16 s-chunks) = 9/CU for memory-level parallelism.
__global__ __launch_bounds__(256) void k_rowsum(const __hip_bfloat16* __restrict__ Q,
                                                const float* __restrict__ rowmin,
                                                float* __restrict__ rowsum) {
    __shared__ float sBrN[64];   // -A2C / (rowmin+eps)
    __shared__ float srs[64];
    const int t  = threadIdx.x;
    const int r0 = (blockIdx.x >> 4) * 64;
    const int s0 = (blockIdx.x & 15) * SCH;
    if (t < 64) {
        sBrN[t] = -A2C / (rowmin[r0 + t] + 1e-5f);
        srs[t]  = 0.f;
    }
    __syncthreads();
    const int roct = (t & 7) * 8;
    const int ss   = t >> 3;          // 0..31
    float brn[8];
    #pragma unroll
    for (int j = 0; j < 8; ++j) brn[j] = sBrN[roct + j];
    const __hip_bfloat16* base = Q + r0 + roct;

    float sums[8] = {};
    #pragma unroll 2
    for (int i = 0; i < SCH / 32; ++i) {
        const int s = s0 + ss + i * 32;
        const us8 v = *reinterpret_cast<const us8*>(base + (size_t)s * S);
        #pragma unroll
        for (int j = 0; j < 8; ++j)
            sums[j] += exp2f(fmaf(brn[j], bf2f(v[j]), A2C));
    }
    #pragma unroll
    for (int j = 0; j < 8; ++j) {
        float x = sums[j];
        x += __shfl_xor(x, 8, 64);
        x += __shfl_xor(x, 16, 64);
        x += __shfl_xor(x, 32, 64);
        if ((t & 63) < 8) atomicAdd(&srs[roct + j], x);
    }
    __syncthreads();
    if (t < 64) atomicAdd(&rowsum[r0 + t], srs[t]);
}

// ---------------- colmax in LOG space (3 ops/elem) -------------
__global__ __launch_bounds__(256) void k_colmax(const __hip_bfloat16* __restrict__ Q,
                                                const float* __restrict__ rowmin,
                                                const float* __restrict__ rowsum,
                                                float* __restrict__ colmaxLog) {
    __shared__ float sBrN[64];
    __shared__ float sCA[64];
    const int t  = threadIdx.x;
    const int r0 = (blockIdx.x >> 4) * 64;
    const int s0 = (blockIdx.x & 15) * SCH;
    if (t < 64) {
        sBrN[t] = -A2C / (rowmin[r0 + t] + 1e-5f);
        sCA[t]  = A2C + 64.0f - __log2f(rowsum[r0 + t]);
    }
    __syncthreads();
    const int roct = (t & 7) * 8;
    const int ss   = t >> 3;
    float brn[8], ca[8];
    #pragma unroll
    for (int j = 0; j < 8; ++j) { brn[j] = sBrN[roct + j]; ca[j] = sCA[roct + j]; }
    const __hip_bfloat16* base = Q + r0 + roct;

    #pragma unroll 2
    for (int i = 0; i < SCH / 32; ++i) {
        const int s = s0 + ss + i * 32;
        const us8 v = *reinterpret_cast<const us8*>(base + (size_t)s * S);
        float mx = -1e30f;
        #pragma unroll
        for (int j = 0; j < 8; ++j)
            mx = fmaxf(mx, fmaf(brn[j], bf2f(v[j]), ca[j]));
        mx = fmaxf(mx, __shfl_xor(mx, 1, 64));
        mx = fmaxf(mx, __shfl_xor(mx, 2, 64));
        mx = fmaxf(mx, __shfl_xor(mx, 4, 64));
        if ((t & 7) == 0)
            atomicMax((unsigned int*)&colmaxLog[s], __float_as_uint(fmaxf(mx, 0.0f)));
    }
}

// ---------------- final: loss = -log(mean_s 2^(cl[s]-64)) ----------------
__global__ __launch_bounds__(256) void k_final(const float* __restrict__ colmaxLog,
                                               float* __restrict__ out) {
    float s = 0.f;
    for (int i = threadIdx.x; i < S; i += 256) s += exp2f(colmaxLog[i]);
    for (int m = 1; m < 64; m <<= 1) s += __shfl_xor(s, m, 64);
    __shared__ float red[4];
    if ((threadIdx.x & 63) == 0) red[threadIdx.x >> 6] = s;
    __syncthreads();
    if (threadIdx.x == 0) {
        const float total = red[0] + red[1] + red[2] + red[3];
        // 2^-64 / S
        out[0] = -logf(total * (5.421010862427522e-20f / (float)S));
    }
}

extern "C" void kernel_launch(void* const* d_in, const int* in_sizes, int n_in,
                              void* d_out, int out_size, void* d_ws, size_t ws_size,
                              hipStream_t stream) {
    const float* img = (const float*)d_in[0];
    const float* gt  = (const float*)d_in[1];

    float* ws        = (float*)d_ws;
    float* meanT     = ws;                  // 256 f
    float* rowmin    = ws + 256;            // S f
    float* rowsum    = rowmin + S;          // S f
    float* colmaxLog = rowsum + S;          // S f
    __hip_bfloat16* A = (__hip_bfloat16*)(colmaxLog + S);
    __hip_bfloat16* B = A + (size_t)S * C;
    __hip_bfloat16* Q = B + (size_t)S * C;   // 170 MB (fits: proven in r4)
    float* ssqP = (float*)Q;                 // [32][S] partials, dead before Q written
    float* out = (float*)d_out;

    k_mean<<<C, 256, 0, stream>>>(gt, meanT);
    k_ssq <<<576, 256, 0, stream>>>(img, gt, meanT, ssqP, A, B,
                                    rowmin, rowsum, colmaxLog);
    k_norm<<<576, 256, 0, stream>>>(ssqP, A, B);

    k_gemm_store<<<864, 256, 0, stream>>>(A, B, rowmin, Q);
    k_rowsum<<<2304, 256, 0, stream>>>(Q, rowmin, rowsum);
    k_colmax<<<2304, 256, 0, stream>>>(Q, rowmin, rowsum, colmaxLog);

    k_final<<<1, 256, 0, stream>>>(colmaxLog, out);
}

// Round 19
// 212.743 us; speedup vs baseline: 1.0406x; 1.0406x over previous
//
#include <hip/hip_runtime.h>
#include <hip/hip_bf16.h>

#define S 9216      // 96*96 spatial positions
#define C 256       // channels
#define NCT 6       // 256-col tiles per block (block = 64 rows x 1536 cols)
#define NG  (NCT*8) // kt-steps per block (48)
#define SCH 1152    // s-chunk for rowsum/colmax kernels

typedef __bf16 bf16x8 __attribute__((ext_vector_type(8)));
typedef float f32x4 __attribute__((ext_vector_type(4)));
typedef unsigned short us8 __attribute__((ext_vector_type(8)));
typedef unsigned short us4 __attribute__((ext_vector_type(4)));

#define GLOAD_LDS16(g, l) __builtin_amdgcn_global_load_lds( \
    (const __attribute__((address_space(1))) void*)(g),     \
    (__attribute__((address_space(3))) void*)(l), 16, 0, 0)

#define A2C 2.8853900817779268f   // 2*log2(e) = 2/ln2

__device__ __forceinline__ float bf2f(unsigned short u) {
    return __uint_as_float(((unsigned)u) << 16);
}
__device__ __forceinline__ unsigned short f2bfbits(float x) {
    __hip_bfloat16 h = __float2bfloat16(x);
    return *reinterpret_cast<unsigned short*>(&h);
}

// ---------------- mean of gt over spatial, per channel ----------------
__global__ __launch_bounds__(256) void k_mean(const float* __restrict__ gt,
                                              float* __restrict__ meanT) {
    const int c = blockIdx.x;
    const float* p = gt + (size_t)c * S;
    float s = 0.f;
    for (int i = threadIdx.x; i < S; i += 256) s += p[i];
    for (int m = 1; m < 64; m <<= 1) s += __shfl_xor(s, m, 64);
    __shared__ float red[4];
    if ((threadIdx.x & 63) == 0) red[threadIdx.x >> 6] = s;
    __syncthreads();
    if (threadIdx.x == 0)
        meanT[c] = (red[0] + red[1] + red[2] + red[3]) * (1.0f / S);
}

// ------- partial centered sum-of-squares over 16-channel parts ----
// 576 blocks (16 parts x 36 s-blocks); fused reduction-buffer init.
__global__ __launch_bounds__(256) void k_ssq(const float* __restrict__ img,
                                             const float* __restrict__ gt,
                                             const float* __restrict__ meanT,
                                             float* __restrict__ ssqP,     // [32][S]
                                             float* __restrict__ rowmin,
                                             float* __restrict__ rowsum,
                                             float* __restrict__ colmaxLog) {
    __shared__ float sm[16];
    const int part = blockIdx.x & 15;
    const int sb   = blockIdx.x >> 4;
    const int t    = threadIdx.x;
    if (t < 16) sm[t] = meanT[part * 16 + t];
    const int s = sb * 256 + t;
    if (part == 0) {
        rowmin[s]    = __uint_as_float(0x7f800000u);  // +inf
        rowsum[s]    = 0.f;
        colmaxLog[s] = 0.f;    // biased log2 max; 0 == 2^-64 ~ 0
    }
    __syncthreads();
    float si = 0.f, st = 0.f;
    #pragma unroll 8
    for (int k = 0; k < 16; ++k) {
        const int c = part * 16 + k;
        const float m  = sm[k];
        const float di = img[(size_t)c * S + s] - m;
        const float dt = gt [(size_t)c * S + s] - m;
        si += di * di;
        st += dt * dt;
    }
    ssqP[(size_t)part * S + s]        = si;
    ssqP[(size_t)(part + 16) * S + s] = st;
}

// ---------------- write normalized bf16 A,B (transposed to [S][C]) --------
__global__ __launch_bounds__(256) void k_write(const float* __restrict__ img,
                                               const float* __restrict__ gt,
                                               const float* __restrict__ meanT,
                                               const float* __restrict__ ssqP,
                                               __hip_bfloat16* __restrict__ A,
                                               __hip_bfloat16* __restrict__ B) {
    __shared__ float sm[16];
    const int part = blockIdx.x & 15;
    const int sb   = blockIdx.x >> 4;
    const int t    = threadIdx.x;
    if (t < 16) sm[t] = meanT[part * 16 + t];
    __syncthreads();
    const int s = sb * 256 + t;
    float si = 0.f, st = 0.f;
    #pragma unroll
    for (int p = 0; p < 16; ++p) {
        si += ssqP[(size_t)p * S + s];
        st += ssqP[(size_t)(p + 16) * S + s];
    }
    const float ri = 1.0f / fmaxf(sqrtf(si), 1e-12f);
    const float rt = 1.0f / fmaxf(sqrtf(st), 1e-12f);
    const int c0 = part * 16;
    #pragma unroll
    for (int cc = 0; cc < 2; ++cc) {
        us8 va, vb;
        #pragma unroll
        for (int e = 0; e < 8; ++e) {
            const int c = c0 + cc * 8 + e;
            const float m = sm[cc * 8 + e];
            va[e] = f2bfbits((img[(size_t)c * S + s] - m) * ri);
            vb[e] = f2bfbits((gt [(size_t)c * S + s] - m) * rt);
        }
        *reinterpret_cast<us8*>(A + (size_t)s * C + c0 + cc * 8) = va;
        *reinterpret_cast<us8*>(B + (size_t)s * C + c0 + cc * 8) = vb;
    }
}

// ---------------- GEMM pass: store raw^T + rowmin (r17, frozen) -------------
// Nine structural variants (r7-r17) all land 105-137us with every pipe <25%;
// this 2-buffer barrier-free ring is the measured best (~105us).
__global__ __launch_bounds__(256, 3) void k_gemm_store(const __hip_bfloat16* __restrict__ A,
                                                       const __hip_bfloat16* __restrict__ B,
                                                       float* __restrict__ rowmin,
                                                       __hip_bfloat16* __restrict__ Q) {
    __shared__ alignas(16) __hip_bfloat16 As[64 * 256];        // 32 KB
    __shared__ alignas(16) __hip_bfloat16 Bs[4 * 2 * 2048];    // 32 KB
    const int tid  = threadIdx.x;
    const int lane = tid & 63;
    const int wid  = tid >> 6;
    const int orig = blockIdx.x;
    const int xcd  = orig & 7;
    const int q    = orig >> 3;                  // 0..107
    const int colGroup = q / 18;                 // 0..5
    const int strip    = xcd * 18 + (q % 18);    // 0..143
    const int rowBase = strip * 64;
    const int cb0     = colGroup * 1536;

    const int frow = lane & 15;
    const int kgrp = lane >> 4;

    {
        const int arow_lo = lane >> 5;
        const int achunk  = lane & 31;
        #pragma unroll
        for (int j = 0; j < 8; ++j) {
            const int row = wid * 16 + j * 2 + arow_lo;
            const int cc  = achunk ^ (row & 7);
            GLOAD_LDS16(A + (size_t)(rowBase + row) * C + cc * 8,
                        &As[(wid * 16 + j * 2) * 256 + lane * 8]);
        }
    }
    const int bcol4  = lane >> 2;
    const int bchunk = (lane & 3) ^ ((lane >> 3) & 3);
    __hip_bfloat16* const BsW = &Bs[wid * 4096];
    const __hip_bfloat16* const Bsrc = B + (size_t)(cb0 + wid * 64) * C;

#define STAGE_B(tt, kk, bb) do {                                              \
    _Pragma("unroll")                                                         \
    for (int i_ = 0; i_ < 4; ++i_) {                                          \
        GLOAD_LDS16(Bsrc + (size_t)((tt) * 256 + i_ * 16 + bcol4) * C         \
                         + (kk) * 32 + bchunk * 8,                            \
                    &BsW[(bb) * 2048 + i_ * 512]);                            \
    } } while (0)

    // prologue: stages g=0,1 -> bufs 0,1
    STAGE_B(0, 0, 0);
    STAGE_B(0, 1, 1);

    // A(8) oldest, B0(4), B1(4): want A+B0 done -> newer = B1 -> vmcnt(4).
    asm volatile("s_waitcnt vmcnt(4)" ::: "memory");
    __builtin_amdgcn_s_barrier();

    const int bswz = (kgrp ^ ((frow >> 1) & 3)) * 8;

    float vmin[4][4];
    #pragma unroll
    for (int m = 0; m < 4; ++m)
        #pragma unroll
        for (int qq = 0; qq < 4; ++qq) vmin[m][qq] = 1e30f;

    for (int t = 0; t < NCT; ++t) {
        f32x4 acc[4][4] = {};
        #pragma unroll
        for (int kt = 0; kt < 8; ++kt) {
            // counted vmcnt (in-order retire; stage = 4 loads, epilogue = 16
            // stores): steady: 1 newer stage -> 4; first two kts after an
            // epilogue: +16 stores -> 20; last-tile tail: kt7 -> 0.
            if (t > 0 && kt < 2)               asm volatile("s_waitcnt vmcnt(20)" ::: "memory");
            else if (t == NCT - 1 && kt == 7)  asm volatile("s_waitcnt vmcnt(0)"  ::: "memory");
            else                               asm volatile("s_waitcnt vmcnt(4)"  ::: "memory");

            const int bufc = kt & 1;

            bf16x8 af[4], bfr[4];
            #pragma unroll
            for (int m = 0; m < 4; ++m) {
                const int row = m * 16 + frow;
                const int p   = (kt * 4 + kgrp) ^ (frow & 7);
                af[m] = *reinterpret_cast<const bf16x8*>(&As[row * 256 + p * 8]);
            }
            #pragma unroll
            for (int n = 0; n < 4; ++n)
                bfr[n] = *reinterpret_cast<const bf16x8*>(
                    &BsW[bufc * 2048 + (n * 16 + frow) * 32 + bswz]);

            // fence: ds_reads complete before buf[bufc] is restaged (rule 18)
            asm volatile("s_waitcnt lgkmcnt(0)" ::: "memory");
            __builtin_amdgcn_sched_barrier(0);

            if (kt <= 5) {
                STAGE_B(t, kt + 2, bufc);
            } else if (t + 1 < NCT) {
                STAGE_B(t + 1, kt - 6, bufc);
            }

            #pragma unroll
            for (int m = 0; m < 4; ++m)
                #pragma unroll
                for (int n = 0; n < 4; ++n)
                    acc[m][n] = __builtin_amdgcn_mfma_f32_16x16x32_bf16(af[m], bfr[n], acc[m][n], 0, 0, 0);
        }

        // ---- epilogue tile t: 16 us4 stores/wave (atomics deferred)
        // C/D map: r_local = m*16 + kgrp*4 + q, col = cb0+t*256+wid*64+n*16+frow
        const int colBase = cb0 + t * 256;
        #pragma unroll
        for (int n = 0; n < 4; ++n) {
            const int cg = colBase + wid * 64 + n * 16 + frow;
            #pragma unroll
            for (int m = 0; m < 4; ++m) {
                us4 pk;
                #pragma unroll
                for (int qq = 0; qq < 4; ++qq) {
                    const float raw = fmaxf(0.5f * (1.0f - acc[m][n][qq]), 0.0f);
                    vmin[m][qq] = fminf(vmin[m][qq], raw);
                    pk[qq] = f2bfbits(raw);
                }
                *reinterpret_cast<us4*>(Q + (size_t)cg * S + rowBase + m * 16 + kgrp * 4) = pk;
            }
        }
    }
#undef STAGE_B

    // ---- deferred rowmin atomics (once per block)
    #pragma unroll
    for (int m = 0; m < 4; ++m)
        #pragma unroll
        for (int qq = 0; qq < 4; ++qq) {
            float v = vmin[m][qq];
            v = fminf(v, __shfl_xor(v, 1, 64));
            v = fminf(v, __shfl_xor(v, 2, 64));
            v = fminf(v, __shfl_xor(v, 4, 64));
            v = fminf(v, __shfl_xor(v, 8, 64));
            if (frow == 0)
                atomicMin((unsigned int*)&rowmin[rowBase + m * 16 + kgrp * 4 + qq],
                          __float_as_uint(v));
        }
}

// ---------------- rowsum over s-chunks (exp2 form; r13-proven) ------------
__global__ __launch_bounds__(256) void k_rowsum(const __hip_bfloat16* __restrict__ Q,
                                                const float* __restrict__ rowmin,
                                                float* __restrict__ rowsum) {
    __shared__ float sBrN[64];   // -A2C / (rowmin+eps)
    __shared__ float srs[64];
    const int t  = threadIdx.x;
    const int r0 = (blockIdx.x >> 3) * 64;
    const int s0 = (blockIdx.x & 7) * SCH;
    if (t < 64) {
        sBrN[t] = -A2C / (rowmin[r0 + t] + 1e-5f);
        srs[t]  = 0.f;
    }
    __syncthreads();
    const int roct = (t & 7) * 8;
    const int ss   = t >> 3;          // 0..31
    float brn[8];
    #pragma unroll
    for (int j = 0; j < 8; ++j) brn[j] = sBrN[roct + j];
    const __hip_bfloat16* base = Q + r0 + roct;

    float sums[8] = {};
    #pragma unroll 4
    for (int i = 0; i < SCH / 32; ++i) {
        const int s = s0 + ss + i * 32;
        const us8 v = *reinterpret_cast<const us8*>(base + (size_t)s * S);
        #pragma unroll
        for (int j = 0; j < 8; ++j)
            sums[j] += exp2f(fmaf(brn[j], bf2f(v[j]), A2C));
    }
    #pragma unroll
    for (int j = 0; j < 8; ++j) {
        float x = sums[j];
        x += __shfl_xor(x, 8, 64);
        x += __shfl_xor(x, 16, 64);
        x += __shfl_xor(x, 32, 64);
        if ((t & 63) < 8) atomicAdd(&srs[roct + j], x);
    }
    __syncthreads();
    if (t < 64) atomicAdd(&rowsum[r0 + t], srs[t]);
}

// ---------------- colmax in LOG space (3 ops/elem; r13-proven) -------------
__global__ __launch_bounds__(256) void k_colmax(const __hip_bfloat16* __restrict__ Q,
                                                const float* __restrict__ rowmin,
                                                const float* __restrict__ rowsum,
                                                float* __restrict__ colmaxLog) {
    __shared__ float sBrN[64];
    __shared__ float sCA[64];
    const int t  = threadIdx.x;
    const int r0 = (blockIdx.x >> 3) * 64;
    const int s0 = (blockIdx.x & 7) * SCH;
    if (t < 64) {
        sBrN[t] = -A2C / (rowmin[r0 + t] + 1e-5f);
        sCA[t]  = A2C + 64.0f - __log2f(rowsum[r0 + t]);
    }
    __syncthreads();
    const int roct = (t & 7) * 8;
    const int ss   = t >> 3;
    float brn[8], ca[8];
    #pragma unroll
    for (int j = 0; j < 8; ++j) { brn[j] = sBrN[roct + j]; ca[j] = sCA[roct + j]; }
    const __hip_bfloat16* base = Q + r0 + roct;

    #pragma unroll 4
    for (int i = 0; i < SCH / 32; ++i) {
        const int s = s0 + ss + i * 32;
        const us8 v = *reinterpret_cast<const us8*>(base + (size_t)s * S);
        float mx = -1e30f;
        #pragma unroll
        for (int j = 0; j < 8; ++j)
            mx = fmaxf(mx, fmaf(brn[j], bf2f(v[j]), ca[j]));
        mx = fmaxf(mx, __shfl_xor(mx, 1, 64));
        mx = fmaxf(mx, __shfl_xor(mx, 2, 64));
        mx = fmaxf(mx, __shfl_xor(mx, 4, 64));
        if ((t & 7) == 0)
            atomicMax((unsigned int*)&colmaxLog[s], __float_as_uint(fmaxf(mx, 0.0f)));
    }
}

// ---------------- final: loss = -log(mean_s 2^(cl[s]-64)) ----------------
__global__ __launch_bounds__(256) void k_final(const float* __restrict__ colmaxLog,
                                               float* __restrict__ out) {
    float s = 0.f;
    for (int i = threadIdx.x; i < S; i += 256) s += exp2f(colmaxLog[i]);
    for (int m = 1; m < 64; m <<= 1) s += __shfl_xor(s, m, 64);
    __shared__ float red[4];
    if ((threadIdx.x & 63) == 0) red[threadIdx.x >> 6] = s;
    __syncthreads();
    if (threadIdx.x == 0) {
        const float total = red[0] + red[1] + red[2] + red[3];
        // 2^-64 / S
        out[0] = -logf(total * (5.421010862427522e-20f / (float)S));
    }
}

extern "C" void kernel_launch(void* const* d_in, const int* in_sizes, int n_in,
                              void* d_out, int out_size, void* d_ws, size_t ws_size,
                              hipStream_t stream) {
    const float* img = (const float*)d_in[0];
    const float* gt  = (const float*)d_in[1];

    float* ws        = (float*)d_ws;
    float* meanT     = ws;                  // 256 f
    float* rowmin    = ws + 256;            // S f
    float* rowsum    = rowmin + S;          // S f
    float* colmaxLog = rowsum + S;          // S f
    __hip_bfloat16* A = (__hip_bfloat16*)(colmaxLog + S);
    __hip_bfloat16* B = A + (size_t)S * C;
    __hip_bfloat16* Q = B + (size_t)S * C;   // 170 MB (fits: proven in r4)
    float* ssqP = (float*)Q;                 // [32][S] partials, dead before Q written
    float* out = (float*)d_out;

    k_mean <<<C, 256, 0, stream>>>(gt, meanT);
    k_ssq  <<<576, 256, 0, stream>>>(img, gt, meanT, ssqP, rowmin, rowsum, colmaxLog);
    k_write<<<576, 256, 0, stream>>>(img, gt, meanT, ssqP, A, B);

    k_gemm_store<<<864, 256, 0, stream>>>(A, B, rowmin, Q);
    k_rowsum<<<1152, 256, 0, stream>>>(Q, rowmin, rowsum);
    k_colmax<<<1152, 256, 0, stream>>>(Q, rowmin, rowsum, colmaxLog);

    k_final<<<1, 256, 0, stream>>>(colmaxLog, out);
}